// Round 2
// baseline (780.011 us; speedup 1.0000x reference)
//
#include <hip/hip_runtime.h>
#include <math.h>

#define NCLS 64
#define FDIM 256
#define EPS_F 1e-8f

#define NQ 131072
#define NS 262144

// ---------------------------------------------------------------------------
// Kernel A: segment-sum support vectors into per-class sums + counts.
// 512 blocks x 256 threads; each block handles 512 rows.
// LDS: 64 classes x 256 dims fp32 accumulator (64 KB) + 64 counts.
// Lane l owns dims {l, l+64, l+128, l+192} -> ds_add bank spread is l%32
// (2-way across 64 lanes = free), global loads are 4x coalesced 256B.
// ---------------------------------------------------------------------------
__global__ __launch_bounds__(256) void seg_sum_kernel(
    const float* __restrict__ support, const int* __restrict__ labels,
    float* __restrict__ proto_sum, float* __restrict__ counts)
{
    extern __shared__ float smem[];
    float* sacc = smem;              // NCLS*FDIM
    float* scnt = smem + NCLS*FDIM;  // NCLS

    const int tid = threadIdx.x;
    for (int i = tid; i < NCLS*FDIM; i += 256) sacc[i] = 0.0f;
    if (tid < NCLS) scnt[tid] = 0.0f;
    __syncthreads();

    const int lane = tid & 63;
    const int wave = tid >> 6;
    const int rows_per_block = NS / gridDim.x;
    const int base = blockIdx.x * rows_per_block;

    for (int r = wave; r < rows_per_block; r += 4) {
        const int row = base + r;
        const int c = labels[row] & (NCLS - 1);
        const float* sp = support + (size_t)row * FDIM;
        #pragma unroll
        for (int j = 0; j < 4; ++j) {
            const float v = sp[lane + 64*j];
            atomicAdd(&sacc[c*FDIM + lane + 64*j], v);   // ds_add_f32
        }
        if (lane == 0) atomicAdd(&scnt[c], 1.0f);
    }
    __syncthreads();

    for (int i = tid; i < NCLS*FDIM; i += 256)
        unsafeAtomicAdd(&proto_sum[i], sacc[i]);          // global_atomic_add_f32
    if (tid < NCLS)
        unsafeAtomicAdd(&counts[tid], scnt[tid]);
}

// ---------------------------------------------------------------------------
// Kernel B: prototypes = proto_sum / max(count,1); normalize by
// max(||p||, eps); store TRANSPOSED PnT[d][c] so kernel C reads 64
// contiguous class weights per k-step (scalarizable uniform loads).
// 64 blocks (one class each) x 64 threads (one wave).
// ---------------------------------------------------------------------------
__global__ __launch_bounds__(64) void proto_norm_kernel(
    const float* __restrict__ proto_sum, const float* __restrict__ counts,
    float* __restrict__ pnT)
{
    const int c = blockIdx.x;
    const int lane = threadIdx.x;
    const float inv = 1.0f / fmaxf(counts[c], 1.0f);

    float p[4];
    float ss = 0.0f;
    #pragma unroll
    for (int j = 0; j < 4; ++j) {
        p[j] = proto_sum[c*FDIM + lane + 64*j] * inv;
        ss += p[j] * p[j];
    }
    #pragma unroll
    for (int off = 32; off > 0; off >>= 1) ss += __shfl_xor(ss, off);
    const float innv = 1.0f / fmaxf(sqrtf(ss), EPS_F);
    #pragma unroll
    for (int j = 0; j < 4; ++j)
        pnT[(size_t)(lane + 64*j) * NCLS + c] = p[j] * innv;
}

// ---------------------------------------------------------------------------
// Kernel C: per-query cosine sims vs all 64 prototypes + log_softmax.
// 512 blocks x 256 threads; one query per thread, acc[64] in VGPRs.
// Q staged via LDS in K-chunks of 64. PnT rows are wave-uniform ->
// scalar loads. ssq (= ||q||^2) accumulated alongside the FMA loop, logits
// scaled by 1/max(||q||,eps) BEFORE log_softmax (the round-1 bug: this
// scale was missing; softmax is not scale-invariant).
// Output row held entirely in-thread -> in-register log_softmax, then
// LDS transpose for coalesced float4 stores.
// ---------------------------------------------------------------------------
#define QSTRIDE 68

__global__ __launch_bounds__(256) void query_kernel(
    const float* __restrict__ query, const float* __restrict__ pnT,
    float* __restrict__ out)
{
    extern __shared__ float qlds[];   // 256 * QSTRIDE floats
    const int tid = threadIdx.x;
    const size_t qbase = (size_t)blockIdx.x * 256;

    float acc[NCLS];
    #pragma unroll
    for (int i = 0; i < NCLS; ++i) acc[i] = 0.0f;
    float ssq = 0.0f;                 // ||q||^2 accumulator

    for (int kc = 0; kc < 4; ++kc) {
        __syncthreads();   // previous chunk fully consumed before overwrite
        // Stage 256 queries x 64 dims: 4096 float4, 16 per thread, coalesced.
        #pragma unroll 4
        for (int i = 0; i < 16; ++i) {
            const int f  = i*256 + tid;
            const int q  = f >> 4;       // 16 float4 per row-chunk
            const int c4 = f & 15;
            const float4 v = *(const float4*)(query + (qbase + q)*FDIM + kc*64 + c4*4);
            *(float4*)&qlds[q*QSTRIDE + c4*4] = v;
        }
        __syncthreads();

        const float* myrow = &qlds[tid * QSTRIDE];
        for (int d = 0; d < 64; ++d) {
            const float qd = myrow[d];
            ssq = fmaf(qd, qd, ssq);
            const float* prow = pnT + (size_t)(kc*64 + d) * NCLS;  // wave-uniform
            #pragma unroll
            for (int c = 0; c < NCLS; ++c)
                acc[c] = fmaf(qd, prow[c], acc[c]);
        }
    }

    // Cosine: divide by max(||q||, eps). (p already normalized in pnT.)
    const float qscale = 1.0f / fmaxf(sqrtf(ssq), EPS_F);
    #pragma unroll
    for (int c = 0; c < NCLS; ++c) acc[c] *= qscale;

    // In-register log_softmax over the 64 logits.
    float m = acc[0];
    #pragma unroll
    for (int c = 1; c < NCLS; ++c) m = fmaxf(m, acc[c]);
    float s = 0.0f;
    #pragma unroll
    for (int c = 0; c < NCLS; ++c) s += __expf(acc[c] - m);
    const float lse = m + __logf(s);

    __syncthreads();   // all compute reads of qlds done
    #pragma unroll
    for (int c = 0; c < NCLS; ++c) qlds[tid*QSTRIDE + c] = acc[c] - lse;
    __syncthreads();

    // Coalesced float4 stores of the 256x64 tile.
    float* ob = out + qbase * NCLS;
    #pragma unroll 4
    for (int j = 0; j < 16; ++j) {
        const int f4 = j*256 + tid;
        const int q  = f4 >> 4;
        const int c4 = f4 & 15;
        const float4 v = *(const float4*)&qlds[q*QSTRIDE + c4*4];
        ((float4*)ob)[f4] = v;
    }
}

// ---------------------------------------------------------------------------
// ws layout (floats): [0,16384) proto_sum | [16384,16448) counts
//                     [16448,32832) pnT
// ---------------------------------------------------------------------------
extern "C" void kernel_launch(void* const* d_in, const int* in_sizes, int n_in,
                              void* d_out, int out_size, void* d_ws, size_t ws_size,
                              hipStream_t stream) {
    const float* support = (const float*)d_in[0];
    const int*   labels  = (const int*)d_in[1];
    const float* query   = (const float*)d_in[2];
    float* out = (float*)d_out;

    float* ws        = (float*)d_ws;
    float* proto_sum = ws;
    float* counts    = ws + NCLS*FDIM;
    float* pnT       = ws + NCLS*FDIM + NCLS;

    // ws is re-poisoned 0xAA before every launch -> zero the accumulators.
    hipMemsetAsync(d_ws, 0, (size_t)(NCLS*FDIM + NCLS) * sizeof(float), stream);

    seg_sum_kernel<<<512, 256, (NCLS*FDIM + NCLS)*sizeof(float), stream>>>(
        support, labels, proto_sum, counts);

    proto_norm_kernel<<<NCLS, 64, 0, stream>>>(proto_sum, counts, pnT);

    query_kernel<<<NQ/256, 256, 256*QSTRIDE*sizeof(float), stream>>>(
        query, pnT, out);
}

// Round 3
// 711.773 us; speedup vs baseline: 1.0959x; 1.0959x over previous
//
#include <hip/hip_runtime.h>
#include <hip/hip_bf16.h>
#include <math.h>

#define NCLS 64
#define FDIM 256
#define EPS_F 1e-8f
#define NQ 131072
#define NS 262144

typedef __attribute__((ext_vector_type(8))) short short8;
typedef __attribute__((ext_vector_type(4))) float f32x4;

__device__ __forceinline__ unsigned short bf16bits(float f) {
    __hip_bfloat16 h = __float2bfloat16(f);
    return *reinterpret_cast<unsigned short*>(&h);
}

// ---------------------------------------------------------------------------
// Kernel A: segment-sum. 256 blocks x 1024 threads (16 waves), 1024 rows/blk.
// Each wave owns 64 rows: 64 labels in ONE coalesced load, then chunks of 4
// rows with all 16 global loads in flight before the LDS atomics (round-2
// failure: VGPR=8, zero ILP, 372us at 5.6% HBM). ds_add addrs = lane%32 ->
// 2-way bank aliasing (free). Flush into npart partial accumulators in ws
// (16-way atomic contention instead of 512-way). Counts via one global
// atomic per lane (each lane owns exactly one row's label).
// ---------------------------------------------------------------------------
__global__ __launch_bounds__(1024) void seg_sum_kernel(
    const float* __restrict__ support, const int* __restrict__ labels,
    float* __restrict__ pa, int set_mask)
{
    __shared__ float sacc[NCLS * FDIM];   // 64 KB exactly
    const int tid = threadIdx.x;
    #pragma unroll
    for (int i = 0; i < 16; ++i) sacc[tid + i * 1024] = 0.0f;
    __syncthreads();

    const int lane = tid & 63;
    const int wave = tid >> 6;
    const int wbase = blockIdx.x * 1024 + wave * 64;   // this wave's 64 rows
    const int mylab = labels[wbase + lane] & (NCLS - 1);

    float* dst = pa + (size_t)(blockIdx.x & set_mask) * 16448;
    unsafeAtomicAdd(&dst[16384 + mylab], 1.0f);        // count, 1 per row

    const float* sp = support + (size_t)wbase * FDIM + lane;
    #pragma unroll 1
    for (int ch = 0; ch < 16; ++ch) {
        const float* p = sp + (size_t)ch * 4 * FDIM;
        float v[4][4];
        #pragma unroll
        for (int r = 0; r < 4; ++r)
            #pragma unroll
            for (int j = 0; j < 4; ++j)
                v[r][j] = p[r * FDIM + j * 64];        // 16 loads in flight
        #pragma unroll
        for (int r = 0; r < 4; ++r) {
            const int c = __shfl(mylab, ch * 4 + r);
            #pragma unroll
            for (int j = 0; j < 4; ++j)
                atomicAdd(&sacc[c * FDIM + j * 64 + lane], v[r][j]);  // ds_add
        }
    }
    __syncthreads();

    #pragma unroll
    for (int i = 0; i < 16; ++i)
        unsafeAtomicAdd(&dst[tid + i * 1024], sacc[tid + i * 1024]);
}

// ---------------------------------------------------------------------------
// Kernel B: sum npart partials, normalize, emit Pn as bf16 B-FRAGMENTS for
// mfma_f32_16x16x32_bf16: frag(ct,kc) is 64 lanes x 16B; lane l holds
// Pn[class=ct*16+(l&15)][k=kc*32+(l>>4)*8 + j], j=0..7.
// 64 blocks (one class) x 256 threads (one dim each).
// ---------------------------------------------------------------------------
__global__ __launch_bounds__(256) void proto_norm_kernel(
    const float* __restrict__ pa, int npart, uint4* __restrict__ pn_frags)
{
    __shared__ float pvec[FDIM];
    __shared__ float ssum[4];
    const int c = blockIdx.x;
    const int d = threadIdx.x;
    const int lane = d & 63;
    const int wv = d >> 6;

    float sum = 0.0f;
    #pragma unroll
    for (int s = 0; s < 16; ++s)
        if (s < npart) sum += pa[(size_t)s * 16448 + c * FDIM + d];

    float cv = (lane < npart) ? pa[(size_t)lane * 16448 + 16384 + c] : 0.0f;
    cv += __shfl_xor(cv, 1); cv += __shfl_xor(cv, 2);
    cv += __shfl_xor(cv, 4); cv += __shfl_xor(cv, 8);
    const float cnt = __shfl(cv, 0);

    const float p = sum / fmaxf(cnt, 1.0f);

    float ss = p * p;
    ss += __shfl_xor(ss, 1);  ss += __shfl_xor(ss, 2);
    ss += __shfl_xor(ss, 4);  ss += __shfl_xor(ss, 8);
    ss += __shfl_xor(ss, 16); ss += __shfl_xor(ss, 32);
    if (lane == 0) ssum[wv] = ss;
    __syncthreads();
    const float tot = ssum[0] + ssum[1] + ssum[2] + ssum[3];
    const float innv = 1.0f / fmaxf(sqrtf(tot), EPS_F);
    pvec[d] = p * innv;
    __syncthreads();

    if (d < 32) {
        const int kc = d >> 2, quad = d & 3;
        const float* pp = &pvec[kc * 32 + quad * 8];
        uint w[4];
        #pragma unroll
        for (int jj = 0; jj < 4; ++jj) {
            const uint lo = bf16bits(pp[2 * jj]);
            const uint hi = bf16bits(pp[2 * jj + 1]);
            w[jj] = lo | (hi << 16);
        }
        pn_frags[((c >> 4) * 8 + kc) * 64 + (c & 15) + 16 * quad] =
            make_uint4(w[0], w[1], w[2], w[3]);
    }
}

// ---------------------------------------------------------------------------
// Kernel C: MFMA query GEMM + fused log_softmax. 512 blocks x 256 threads;
// each wave computes its own 64 queries x all 64 classes (4 q-tiles x 4
// c-tiles of 16x16x32 bf16). Pn frags staged LDS once (1 barrier total);
// A-frags loaded fp32 from global (rows hit one 128B line per k-chunk),
// cvt to bf16 in-reg, ssq accumulated from exact fp32 values.
// C layout (m89-verified): col=lane&15 (class), row=quad*4+reg (query).
// ---------------------------------------------------------------------------
__global__ __launch_bounds__(256) void query_kernel(
    const float* __restrict__ query, const uint4* __restrict__ pn_frags,
    float* __restrict__ out)
{
    __shared__ uint4 pnl[2048];   // 32 KB: 32 frags x 64 lanes x 16B
    const int tid = threadIdx.x;
    #pragma unroll
    for (int i = 0; i < 8; ++i) pnl[i * 256 + tid] = pn_frags[i * 256 + tid];
    __syncthreads();

    const int lane = tid & 63;
    const int wave = tid >> 6;
    const int m = lane & 15;
    const int quad = lane >> 4;
    const size_t qb = (size_t)blockIdx.x * 256 + wave * 64;

    f32x4 acc[4][4];
    #pragma unroll
    for (int qt = 0; qt < 4; ++qt)
        #pragma unroll
        for (int ct = 0; ct < 4; ++ct)
            acc[qt][ct] = (f32x4){0.f, 0.f, 0.f, 0.f};
    float ssqv[4] = {0.f, 0.f, 0.f, 0.f};

    for (int kc = 0; kc < 8; ++kc) {
        // B frags for the 4 class tiles at this k-chunk (linear -> no conflicts)
        short8 b[4];
        #pragma unroll
        for (int ct = 0; ct < 4; ++ct)
            b[ct] = *(const short8*)&pnl[(ct * 8 + kc) * 64 + lane];

        // Issue all 8 A-loads (4 q-tiles x 2 float4) before any use.
        f32x4 va[4], vb[4];
        #pragma unroll
        for (int qt = 0; qt < 4; ++qt) {
            const float* qp = query + (qb + qt * 16 + m) * FDIM + kc * 32 + quad * 8;
            va[qt] = *(const f32x4*)qp;
            vb[qt] = *(const f32x4*)(qp + 4);
        }
        #pragma unroll
        for (int qt = 0; qt < 4; ++qt) {
            float vals[8] = {va[qt].x, va[qt].y, va[qt].z, va[qt].w,
                             vb[qt].x, vb[qt].y, vb[qt].z, vb[qt].w};
            short8 a;
            #pragma unroll
            for (int j = 0; j < 8; ++j) {
                ssqv[qt] = fmaf(vals[j], vals[j], ssqv[qt]);
                a[j] = (short)bf16bits(vals[j]);
            }
            #pragma unroll
            for (int ct = 0; ct < 4; ++ct)
                acc[qt][ct] = __builtin_amdgcn_mfma_f32_16x16x32_bf16(
                    a, b[ct], acc[qt][ct], 0, 0, 0);
        }
    }

    // ssqv[qt] covers this lane's quad-slice of query (qt*16 + m); combine quads.
    #pragma unroll
    for (int qt = 0; qt < 4; ++qt) {
        ssqv[qt] += __shfl_xor(ssqv[qt], 16);
        ssqv[qt] += __shfl_xor(ssqv[qt], 32);
    }

    #pragma unroll
    for (int qt = 0; qt < 4; ++qt) {
        #pragma unroll
        for (int reg = 0; reg < 4; ++reg) {
            // lane needs ssq of query row quad*4+reg; it lives at lane id == row.
            const float ssq = __shfl(ssqv[qt], quad * 4 + reg);
            const float qs = 1.0f / fmaxf(sqrtf(ssq), EPS_F);
            float s0 = acc[qt][0][reg] * qs;
            float s1 = acc[qt][1][reg] * qs;
            float s2 = acc[qt][2][reg] * qs;
            float s3 = acc[qt][3][reg] * qs;
            // softmax over 64 classes = 4 regs here x 16 lanes of this quad
            float mx = fmaxf(fmaxf(s0, s1), fmaxf(s2, s3));
            mx = fmaxf(mx, __shfl_xor(mx, 1));
            mx = fmaxf(mx, __shfl_xor(mx, 2));
            mx = fmaxf(mx, __shfl_xor(mx, 4));
            mx = fmaxf(mx, __shfl_xor(mx, 8));
            float e = __expf(s0 - mx) + __expf(s1 - mx) +
                      __expf(s2 - mx) + __expf(s3 - mx);
            e += __shfl_xor(e, 1);
            e += __shfl_xor(e, 2);
            e += __shfl_xor(e, 4);
            e += __shfl_xor(e, 8);
            const float lse = mx + __logf(e);
            float* op = out + (qb + qt * 16 + quad * 4 + reg) * 64 + m;
            op[0]  = s0 - lse;
            op[16] = s1 - lse;
            op[32] = s2 - lse;
            op[48] = s3 - lse;
        }
    }
}

// ---------------------------------------------------------------------------
// ws layout (floats): [0, npart*16448) partial sums+counts | then pn_frags
// (32 KB, 16B-aligned). npart=16 if ws fits, else 1 (round-2 ws >= 131 KB).
// ---------------------------------------------------------------------------
extern "C" void kernel_launch(void* const* d_in, const int* in_sizes, int n_in,
                              void* d_out, int out_size, void* d_ws, size_t ws_size,
                              hipStream_t stream) {
    const float* support = (const float*)d_in[0];
    const int*   labels  = (const int*)d_in[1];
    const float* query   = (const float*)d_in[2];
    float* out = (float*)d_out;

    float* ws = (float*)d_ws;
    const int npart = (ws_size >= (size_t)16 * 16448 * 4 + 32768) ? 16 : 1;
    float* pa = ws;
    uint4* pn_frags = (uint4*)(ws + (size_t)npart * 16448);

    hipMemsetAsync(pa, 0, (size_t)npart * 16448 * sizeof(float), stream);

    seg_sum_kernel<<<256, 1024, 0, stream>>>(support, labels, pa, npart - 1);
    proto_norm_kernel<<<NCLS, 256, 0, stream>>>(pa, npart, pn_frags);
    query_kernel<<<NQ / 256, 256, 0, stream>>>(query, pn_frags, out);
}

// Round 4
// 706.959 us; speedup vs baseline: 1.1033x; 1.0068x over previous
//
#include <hip/hip_runtime.h>
#include <hip/hip_bf16.h>
#include <math.h>

#define NCLS 64
#define FDIM 256
#define EPS_F 1e-8f
#define NQ 131072
#define NS 262144

typedef __attribute__((ext_vector_type(8))) short short8;
typedef __attribute__((ext_vector_type(4))) float f32x4;

__device__ __forceinline__ unsigned short bf16bits(float f) {
    __hip_bfloat16 h = __float2bfloat16(f);
    return *reinterpret_cast<unsigned short*>(&h);
}

// ---------------------------------------------------------------------------
// Kernel A: segment-sum. 256 blocks x 1024 threads (16 waves), 1024 rows/blk.
// One float4 load per ROW (64 lanes x 16B = the whole 1KB row, coalesced).
// Manual 2-stage pipeline in NAMED registers: chunk ch+1's 4 loads are issued
// before chunk ch's LDS atomics in program order, so the atomic scheduling
// fence (round-2/3 failure: VGPR=16, serialized latency, 365us @ 4.6% HBM)
// cannot serialize them. LDS ds_add at c*256+4*lane+k: 8-way bank alias
// (~2.9x) but ~12us/block hides under the 43us HBM floor.
// Counts: one global f32 atomic per row (worked in round 3, tiny).
// ---------------------------------------------------------------------------
__global__ __launch_bounds__(1024) void seg_sum_kernel(
    const float* __restrict__ support, const int* __restrict__ labels,
    float* __restrict__ pa, int set_mask)
{
    __shared__ float sacc[NCLS * FDIM];   // 64 KB exactly
    const int tid = threadIdx.x;
    #pragma unroll
    for (int i = 0; i < 16; ++i) sacc[tid + i * 1024] = 0.0f;
    __syncthreads();

    const int lane = tid & 63;
    const int wave = tid >> 6;
    const int wbase = blockIdx.x * 1024 + wave * 64;   // this wave's 64 rows
    const int mylab = labels[wbase + lane] & (NCLS - 1);

    float* dst = pa + (size_t)(blockIdx.x & set_mask) * 16448;
    unsafeAtomicAdd(&dst[16384 + mylab], 1.0f);        // count, 1 per row

    const float4* sp = (const float4*)support + (size_t)wbase * 64 + lane;

    float4 c0 = sp[0 * 64], c1 = sp[1 * 64], c2 = sp[2 * 64], c3 = sp[3 * 64];

    #pragma unroll 1
    for (int ch = 0; ch < 16; ++ch) {
        float4 n0, n1, n2, n3;
        if (ch < 15) {
            const float4* np = sp + (size_t)(ch + 1) * 4 * 64;
            n0 = np[0 * 64]; n1 = np[1 * 64]; n2 = np[2 * 64]; n3 = np[3 * 64];
        }
        int cc;
        cc = __shfl(mylab, ch * 4 + 0);
        atomicAdd(&sacc[cc * FDIM + lane * 4 + 0], c0.x);
        atomicAdd(&sacc[cc * FDIM + lane * 4 + 1], c0.y);
        atomicAdd(&sacc[cc * FDIM + lane * 4 + 2], c0.z);
        atomicAdd(&sacc[cc * FDIM + lane * 4 + 3], c0.w);
        cc = __shfl(mylab, ch * 4 + 1);
        atomicAdd(&sacc[cc * FDIM + lane * 4 + 0], c1.x);
        atomicAdd(&sacc[cc * FDIM + lane * 4 + 1], c1.y);
        atomicAdd(&sacc[cc * FDIM + lane * 4 + 2], c1.z);
        atomicAdd(&sacc[cc * FDIM + lane * 4 + 3], c1.w);
        cc = __shfl(mylab, ch * 4 + 2);
        atomicAdd(&sacc[cc * FDIM + lane * 4 + 0], c2.x);
        atomicAdd(&sacc[cc * FDIM + lane * 4 + 1], c2.y);
        atomicAdd(&sacc[cc * FDIM + lane * 4 + 2], c2.z);
        atomicAdd(&sacc[cc * FDIM + lane * 4 + 3], c2.w);
        cc = __shfl(mylab, ch * 4 + 3);
        atomicAdd(&sacc[cc * FDIM + lane * 4 + 0], c3.x);
        atomicAdd(&sacc[cc * FDIM + lane * 4 + 1], c3.y);
        atomicAdd(&sacc[cc * FDIM + lane * 4 + 2], c3.z);
        atomicAdd(&sacc[cc * FDIM + lane * 4 + 3], c3.w);
        c0 = n0; c1 = n1; c2 = n2; c3 = n3;
    }
    __syncthreads();

    #pragma unroll
    for (int i = 0; i < 16; ++i)
        unsafeAtomicAdd(&dst[tid + i * 1024], sacc[tid + i * 1024]);
}

// ---------------------------------------------------------------------------
// Kernel B: sum npart partials, normalize, emit Pn as bf16 B-FRAGMENTS for
// mfma_f32_16x16x32_bf16 (unchanged from round 3 — verified correct).
// ---------------------------------------------------------------------------
__global__ __launch_bounds__(256) void proto_norm_kernel(
    const float* __restrict__ pa, int npart, uint4* __restrict__ pn_frags)
{
    __shared__ float pvec[FDIM];
    __shared__ float ssum[4];
    const int c = blockIdx.x;
    const int d = threadIdx.x;
    const int lane = d & 63;
    const int wv = d >> 6;

    float sum = 0.0f;
    #pragma unroll
    for (int s = 0; s < 16; ++s)
        if (s < npart) sum += pa[(size_t)s * 16448 + c * FDIM + d];

    float cv = (lane < npart) ? pa[(size_t)lane * 16448 + 16384 + c] : 0.0f;
    cv += __shfl_xor(cv, 1); cv += __shfl_xor(cv, 2);
    cv += __shfl_xor(cv, 4); cv += __shfl_xor(cv, 8);
    const float cnt = __shfl(cv, 0);

    const float p = sum / fmaxf(cnt, 1.0f);

    float ss = p * p;
    ss += __shfl_xor(ss, 1);  ss += __shfl_xor(ss, 2);
    ss += __shfl_xor(ss, 4);  ss += __shfl_xor(ss, 8);
    ss += __shfl_xor(ss, 16); ss += __shfl_xor(ss, 32);
    if (lane == 0) ssum[wv] = ss;
    __syncthreads();
    const float tot = ssum[0] + ssum[1] + ssum[2] + ssum[3];
    const float innv = 1.0f / fmaxf(sqrtf(tot), EPS_F);
    pvec[d] = p * innv;
    __syncthreads();

    if (d < 32) {
        const int kc = d >> 2, quad = d & 3;
        const float* pp = &pvec[kc * 32 + quad * 8];
        uint w0 = bf16bits(pp[0]) | ((uint)bf16bits(pp[1]) << 16);
        uint w1 = bf16bits(pp[2]) | ((uint)bf16bits(pp[3]) << 16);
        uint w2 = bf16bits(pp[4]) | ((uint)bf16bits(pp[5]) << 16);
        uint w3 = bf16bits(pp[6]) | ((uint)bf16bits(pp[7]) << 16);
        pn_frags[((c >> 4) * 8 + kc) * 64 + (c & 15) + 16 * quad] =
            make_uint4(w0, w1, w2, w3);
    }
}

// ---------------------------------------------------------------------------
// Kernel C: MFMA query GEMM + fused log_softmax. 2048 blocks x 256 threads
// (4 waves); block tile = 64 queries, wave owns 16 queries x all 64 classes.
// Q staged via COALESCED float4 loads -> bf16 LDS rows (stride 272 bf16:
// 16B-aligned b128 frag reads, ~4-way banks). B-frags read lane-linear from
// global pn_frags (32 KB, L1-hot). NO indexed per-thread arrays anywhere
// (round-3 suspect: scratch spills) — all frags/accs are named variables,
// software-pipelined one kc ahead. ssq from bf16 A-frags (err ~1e-4).
// C layout (verified round 3): col=lane&15 (class), row=quad*4+reg (query).
// ---------------------------------------------------------------------------
#define QSTR 272   // bf16 elements per LDS row (544 B, multiple of 16 B)

__global__ __launch_bounds__(256) void query_kernel(
    const float* __restrict__ query, const uint4* __restrict__ pn_frags,
    float* __restrict__ out)
{
    __shared__ unsigned short Qb[64 * QSTR];   // 34816 B
    const int tid = threadIdx.x;
    const int lane = tid & 63;
    const int wave = tid >> 6;
    const size_t qb0 = (size_t)blockIdx.x * 64;

    // Stage: iteration i handles row i*4+wave; 64 lanes cover the whole row.
    #pragma unroll
    for (int i = 0; i < 16; ++i) {
        const int row = i * 4 + wave;
        const float4 v = ((const float4*)(query + (qb0 + row) * FDIM))[lane];
        const uint lo = bf16bits(v.x) | ((uint)bf16bits(v.y) << 16);
        const uint hi = bf16bits(v.z) | ((uint)bf16bits(v.w) << 16);
        *(uint2*)&Qb[row * QSTR + lane * 4] = make_uint2(lo, hi);
    }
    __syncthreads();

    const int m = lane & 15;
    const int quad = lane >> 4;
    const unsigned short* arow = &Qb[(wave * 16 + m) * QSTR + quad * 8];
    const short8* bp = (const short8*)pn_frags;

    f32x4 acc0 = {0.f,0.f,0.f,0.f}, acc1 = {0.f,0.f,0.f,0.f};
    f32x4 acc2 = {0.f,0.f,0.f,0.f}, acc3 = {0.f,0.f,0.f,0.f};
    float ssq = 0.0f;

    short8 a  = *(const short8*)(arow);
    short8 b0 = bp[(0 * 8 + 0) * 64 + lane];
    short8 b1 = bp[(1 * 8 + 0) * 64 + lane];
    short8 b2 = bp[(2 * 8 + 0) * 64 + lane];
    short8 b3 = bp[(3 * 8 + 0) * 64 + lane];

    #pragma unroll
    for (int kc = 0; kc < 8; ++kc) {
        short8 an, c0, c1, c2, c3;
        const int kn = (kc < 7) ? kc + 1 : 7;
        an = *(const short8*)(arow + kn * 32);
        c0 = bp[(0 * 8 + kn) * 64 + lane];
        c1 = bp[(1 * 8 + kn) * 64 + lane];
        c2 = bp[(2 * 8 + kn) * 64 + lane];
        c3 = bp[(3 * 8 + kn) * 64 + lane];

        // ||q|| partial from this lane's 8 bf16 elements (row m, quad slice).
        float x0 = __uint_as_float(((uint)(unsigned short)a[0]) << 16);
        float x1 = __uint_as_float(((uint)(unsigned short)a[1]) << 16);
        float x2 = __uint_as_float(((uint)(unsigned short)a[2]) << 16);
        float x3 = __uint_as_float(((uint)(unsigned short)a[3]) << 16);
        float x4 = __uint_as_float(((uint)(unsigned short)a[4]) << 16);
        float x5 = __uint_as_float(((uint)(unsigned short)a[5]) << 16);
        float x6 = __uint_as_float(((uint)(unsigned short)a[6]) << 16);
        float x7 = __uint_as_float(((uint)(unsigned short)a[7]) << 16);
        ssq = fmaf(x0, x0, ssq); ssq = fmaf(x1, x1, ssq);
        ssq = fmaf(x2, x2, ssq); ssq = fmaf(x3, x3, ssq);
        ssq = fmaf(x4, x4, ssq); ssq = fmaf(x5, x5, ssq);
        ssq = fmaf(x6, x6, ssq); ssq = fmaf(x7, x7, ssq);

        acc0 = __builtin_amdgcn_mfma_f32_16x16x32_bf16(a, b0, acc0, 0, 0, 0);
        acc1 = __builtin_amdgcn_mfma_f32_16x16x32_bf16(a, b1, acc1, 0, 0, 0);
        acc2 = __builtin_amdgcn_mfma_f32_16x16x32_bf16(a, b2, acc2, 0, 0, 0);
        acc3 = __builtin_amdgcn_mfma_f32_16x16x32_bf16(a, b3, acc3, 0, 0, 0);

        a = an; b0 = c0; b1 = c1; b2 = c2; b3 = c3;
    }

    // Combine quad slices: lane ends with full ssq of query row (lane&15).
    ssq += __shfl_xor(ssq, 16);
    ssq += __shfl_xor(ssq, 32);

    const size_t qbw = qb0 + wave * 16;
    #pragma unroll
    for (int reg = 0; reg < 4; ++reg) {
        const float rssq = __shfl(ssq, quad * 4 + reg);
        const float qs = 1.0f / fmaxf(sqrtf(rssq), EPS_F);
        float s0 = acc0[reg] * qs;
        float s1 = acc1[reg] * qs;
        float s2 = acc2[reg] * qs;
        float s3 = acc3[reg] * qs;
        float mx = fmaxf(fmaxf(s0, s1), fmaxf(s2, s3));
        mx = fmaxf(mx, __shfl_xor(mx, 1));
        mx = fmaxf(mx, __shfl_xor(mx, 2));
        mx = fmaxf(mx, __shfl_xor(mx, 4));
        mx = fmaxf(mx, __shfl_xor(mx, 8));
        float e = __expf(s0 - mx) + __expf(s1 - mx) +
                  __expf(s2 - mx) + __expf(s3 - mx);
        e += __shfl_xor(e, 1);
        e += __shfl_xor(e, 2);
        e += __shfl_xor(e, 4);
        e += __shfl_xor(e, 8);
        const float lse = mx + __logf(e);
        float* op = out + (qbw + quad * 4 + reg) * 64 + m;
        op[0]  = s0 - lse;
        op[16] = s1 - lse;
        op[32] = s2 - lse;
        op[48] = s3 - lse;
    }
}

// ---------------------------------------------------------------------------
// ws layout (floats): [0, npart*16448) partial sums+counts | then pn_frags
// (32 KB, 16B-aligned).
// ---------------------------------------------------------------------------
extern "C" void kernel_launch(void* const* d_in, const int* in_sizes, int n_in,
                              void* d_out, int out_size, void* d_ws, size_t ws_size,
                              hipStream_t stream) {
    const float* support = (const float*)d_in[0];
    const int*   labels  = (const int*)d_in[1];
    const float* query   = (const float*)d_in[2];
    float* out = (float*)d_out;

    float* ws = (float*)d_ws;
    const int npart = (ws_size >= (size_t)16 * 16448 * 4 + 32768) ? 16 : 1;
    float* pa = ws;
    uint4* pn_frags = (uint4*)(ws + (size_t)npart * 16448);

    hipMemsetAsync(pa, 0, (size_t)npart * 16448 * sizeof(float), stream);

    seg_sum_kernel<<<256, 1024, 0, stream>>>(support, labels, pa, npart - 1);
    proto_norm_kernel<<<NCLS, 256, 0, stream>>>(pa, npart, pn_frags);
    query_kernel<<<NQ / 64, 256, 0, stream>>>(query, pn_frags, out);
}